// Round 10
// baseline (211.238 us; speedup 1.0000x reference)
//
#include <hip/hip_runtime.h>
#include <hip/hip_fp16.h>

#define DIM 64
#define NEG_SLOPE 0.01f
#define BKT 256          // nodes per bucket (LDS hist granularity in k_bucket)
#define TILEP 4096       // symmetric PAIRS per hist/place tile (= 8192 records)
#define RECS (TILEP * 2) // records per tile
#define STILE 2048       // scan1 tile: 256 thr x 8

typedef unsigned u32;
typedef unsigned short u16;
typedef unsigned char u8;

// ---------------------------------------------------------------------------
// Round 18: consolidation. Convs are HBM-random-line-bound (R13/15/16/17:
// 4 MLP structures, 35-163 in-flight loads/CU, all converge 3.3-3.9 TB/s;
// conv2's random-miss residue ~39MB at ~2.3TB/s = random-HBM efficiency
// ceiling). fp8 rejected: absmax 2^-8 constant across rounds = threshold,
// no margin for fp8's aligned worst case. Build: R17's reshuffle measured
// worse than R13 (209 vs 204, convs identical) -> revert to R13's exact
// build (TILEP 4096, separate scanfix), keep the one unambiguous win:
// k_bucket stages pay/loc8 in LDS once (-6MB global re-reads).
// ---------------------------------------------------------------------------

__global__ void k_norm_hist(const float* __restrict__ emb,
                            __half* __restrict__ x0h,
                            const int* __restrict__ p,
                            u32* __restrict__ mat,
                            int N, int E, int rb, int B, int nblkE) {
    int t = threadIdx.x;
    if ((int)blockIdx.x < rb) {
        // L2-normalize: 16 lanes/row, 4 rows/wave, 8 waves -> 32 rows/block
        int lane = t & 63;
        int row  = blockIdx.x * 32 + (t >> 6) * 4 + (lane >> 4);
        int l16  = lane & 15;
        if (row >= N) return;
        float4 v = *(const float4*)(emb + (size_t)row * DIM + l16 * 4);
        float s = v.x * v.x + v.y * v.y + v.z * v.z + v.w * v.w;
        #pragma unroll
        for (int m = 1; m < 16; m <<= 1) s += __shfl_xor(s, m, 64);
        float inv = 1.0f / fmaxf(sqrtf(s), 1e-12f);
        union { uint2 u; __half2 h[2]; } pk;
        pk.h[0] = __floats2half2_rn(v.x * inv, v.y * inv);
        pk.h[1] = __floats2half2_rn(v.z * inv, v.w * inv);
        *(uint2*)(x0h + (size_t)row * DIM + l16 * 4) = pk.u;
    } else {
        __shared__ u32 hist[800];           // B = 782 bins
        int blk = blockIdx.x - rb;
        for (int i = t; i < B; i += 512) hist[i] = 0;
        __syncthreads();
        int base = blk * TILEP;
        #pragma unroll
        for (int k = 0; k < TILEP / 512; k++) {
            int pe = base + k * 512 + t;
            if (pe < E) {
                int a = p[pe];
                int b = p[pe + E];
                atomicAdd(&hist[(u32)b >> 8], 1u);
                atomicAdd(&hist[(u32)a >> 8], 1u);
            }
        }
        __syncthreads();
        for (int i = t; i < B; i += 512) mat[(size_t)i * nblkE + blk] = hist[i];
    }
}

__global__ void k_scan1(const u32* __restrict__ in, u32* __restrict__ out,
                        u32* __restrict__ bsum, int M) {
    __shared__ u32 sdata[256];
    int t = threadIdx.x;
    int base = blockIdx.x * STILE + t * 8;
    u32 v[8]; u32 tsum = 0;
    #pragma unroll
    for (int k = 0; k < 8; k++) {
        int i = base + k;
        v[k] = (i < M) ? in[i] : 0u;
        tsum += v[k];
    }
    sdata[t] = tsum;
    __syncthreads();
    for (int off = 1; off < 256; off <<= 1) {
        u32 x = (t >= off) ? sdata[t - off] : 0u;
        __syncthreads();
        sdata[t] += x;
        __syncthreads();
    }
    u32 run = sdata[t] - tsum;
    if (t == 255) bsum[blockIdx.x] = sdata[255];
    #pragma unroll
    for (int k = 0; k < 8; k++) {
        int i = base + k;
        if (i < M) out[i] = run;
        run += v[k];
    }
}

// fold block offsets into mscan; each block re-scans bsum (nb<=256) in LDS
__global__ void k_scanfix(u32* __restrict__ mscan,
                          const u32* __restrict__ bsum, int nb, int M) {
    __shared__ u32 sdata[256];
    __shared__ u32 sexcl[256];
    int t = threadIdx.x;
    u32 v = (t < nb) ? bsum[t] : 0u;
    sdata[t] = v;
    __syncthreads();
    for (int off = 1; off < 256; off <<= 1) {
        u32 x = (t >= off) ? sdata[t - off] : 0u;
        __syncthreads();
        sdata[t] += x;
        __syncthreads();
    }
    sexcl[t] = sdata[t] - v;
    __syncthreads();
    int i = blockIdx.x * 256 + t;
    if (i < M) mscan[i] += sexcl[i >> 11];
}

// LDS tile sort + coalesced run write-out. ~94KB LDS, 1 block/CU.
__global__ __launch_bounds__(512, 1)
void k_place(const int* __restrict__ p, const float* __restrict__ w,
             const u32* __restrict__ mscan,
             u32* __restrict__ pay, u8* __restrict__ loc8,
             int E, int nblkE, int B) {
    __shared__ u32 sPay[RECS];    // 32KB
    __shared__ u32 sMeta[RECS];   // 32KB (= dst node id; bin=>>8, loc=&255)
    __shared__ u16 sPerm[RECS];   // 16KB
    __shared__ u32 hist[1024];    // counts -> (rezeroed) cursors
    __shared__ u32 sstart[1024];
    __shared__ u32 delta[1024];
    __shared__ u32 sdata[512];

    int blk = blockIdx.x;
    int t = threadIdx.x;
    int base = blk * TILEP;
    int rem = E - base;                       // pairs in this tile
    int vlim = rem * 2; if (vlim > RECS) vlim = RECS;

    hist[t] = 0; hist[t + 512] = 0;
    __syncthreads();

    // pass A: stage records + count bins
    #pragma unroll
    for (int k = 0; k < TILEP / 512; k++) {
        int pe = base + k * 512 + t;
        if (pe < E) {
            int a = p[pe];
            int b = p[pe + E];
            float wf = w[pe];
            float wb = w[pe + E];
            u32 wf14 = (u32)(wf * 16384.0f + 0.5f); if (wf14 > 16383u) wf14 = 16383u;
            u32 wb14 = (u32)(wb * 16384.0f + 0.5f); if (wb14 > 16383u) wb14 = 16383u;
            int li = (k * 512 + t) * 2;
            sPay[li]      = ((u32)a << 14) | wf14;   // fwd record: dst = b
            sMeta[li]     = (u32)b;
            sPay[li + 1]  = ((u32)b << 14) | wb14;   // bwd record: dst = a
            sMeta[li + 1] = (u32)a;
            atomicAdd(&hist[(u32)b >> 8], 1u);
            atomicAdd(&hist[(u32)a >> 8], 1u);
        }
    }
    __syncthreads();

    // scan 1024 bins (2 per thread) -> sstart (exclusive)
    u32 a0 = hist[2 * t], a1 = hist[2 * t + 1];
    u32 tsum = a0 + a1;
    sdata[t] = tsum;
    __syncthreads();
    for (int off = 1; off < 512; off <<= 1) {
        u32 x = (t >= off) ? sdata[t - off] : 0u;
        __syncthreads();
        sdata[t] += x;
        __syncthreads();
    }
    u32 texcl = sdata[t] - tsum;
    sstart[2 * t]     = texcl;
    sstart[2 * t + 1] = texcl + a0;
    __syncthreads();

    // rezero hist (becomes rank cursor) + load this tile's mscan column
    hist[t] = 0; hist[t + 512] = 0;
    for (int i = t; i < B; i += 512)
        delta[i] = mscan[(size_t)i * nblkE + blk] - sstart[i];
    __syncthreads();

    // pass B: build permutation (staging order sorted by bin)
    #pragma unroll
    for (int k = 0; k < RECS / 512; k++) {
        int li = k * 512 + t;
        if (li < vlim) {
            u32 bin = sMeta[li] >> 8;
            u32 r = atomicAdd(&hist[bin], 1u);
            sPerm[sstart[bin] + r] = (u16)li;
        }
    }
    __syncthreads();

    // pass C: write out in sorted order; consecutive j -> consecutive gslot
    #pragma unroll
    for (int k = 0; k < RECS / 512; k++) {
        int j = k * 512 + t;
        if (j < vlim) {
            int li = sPerm[j];
            u32 pv = sPay[li];
            u32 mt = sMeta[li];
            u32 gs = (u32)j + delta[mt >> 8];   // = mscan base + rank (u32 wrap ok)
            pay[gs]  = pv;
            loc8[gs] = (u8)(mt & 255u);
        }
    }
}

__global__ void k_bucket(const u32* __restrict__ pay,
                         const u8* __restrict__ loc8,
                         const u32* __restrict__ mscan,
                         u32* __restrict__ row_ptr,
                         u32* __restrict__ colw,
                         int N, int E, int B, int nblkE) {
    __shared__ u32 hist[BKT];
    __shared__ u32 excl[BKT];
    __shared__ u32 sdata[256];
    __shared__ u32 spay[2048];   // 8KB: staged records (span ~1535)
    __shared__ u8  sloc[2048];   // 2KB
    int b = blockIdx.x;
    int t = threadIdx.x;
    int node0 = b * BKT;
    int nnodes = N - node0; if (nnodes > BKT) nnodes = BKT;
    size_t flat0 = (size_t)b * nblkE;
    u32 seg_s = mscan[flat0];
    u32 seg_e = (b + 1 < B) ? mscan[flat0 + nblkE] : (u32)(2 * E);
    u32 span = seg_e - seg_s;
    u32 nst  = span < 2048u ? span : 2048u;

    hist[t] = 0;
    __syncthreads();
    // stage records once (R17's proven win: one global read instead of two)
    for (u32 j = t; j < nst; j += 256) {
        spay[j] = pay[seg_s + j];
        sloc[j] = loc8[seg_s + j];
    }
    __syncthreads();
    for (u32 j = t; j < span; j += 256) {
        u32 loc = (j < nst) ? (u32)sloc[j] : (u32)loc8[seg_s + j];
        atomicAdd(&hist[loc], 1u);
    }
    __syncthreads();
    u32 tsum = hist[t];
    sdata[t] = tsum;
    __syncthreads();
    for (int off = 1; off < 256; off <<= 1) {
        u32 x = (t >= off) ? sdata[t - off] : 0u;
        __syncthreads();
        sdata[t] += x;
        __syncthreads();
    }
    u32 texcl = sdata[t] - tsum;
    excl[t] = texcl;
    if (t < nnodes) row_ptr[node0 + t] = seg_s + texcl;
    if (b == 0 && t == 0) row_ptr[N] = (u32)(2 * E);
    __syncthreads();
    for (u32 j = t; j < span; j += 256) {
        u32 loc, pv;
        if (j < nst) { loc = sloc[j]; pv = spay[j]; }
        else         { loc = loc8[seg_s + j]; pv = pay[seg_s + j]; }
        u32 pos = atomicAdd(&excl[loc], 1u);
        colw[seg_s + pos] = pv;
    }
}

// --- conv: 8 rows/wave, 8 lanes/row, lane covers dims [sub*8, sub*8+8) ----
// Simple m-loop gather (proven equal-best: VGPR 24, ~58% occ, conv2 41.7us;
// conv is HBM-random-line-bound, more MLP does not help — R15/R16).

__device__ __forceinline__ void gather8(const __half* __restrict__ x,
                                        const u32* __restrict__ colw,
                                        u32 s, u32 e, int g, int sub,
                                        float acc[8]) {
    for (u32 base = s; base < e; base += 8) {
        int m = (int)(e - base); if (m > 8) m = 8;   // valid edges this chunk
        u32 u = 0;
        if (sub < m) u = colw[base + sub];
        int   cx = (int)(u >> 14);
        float cy = (float)(u & 16383u) * (1.0f / 16384.0f);
        for (int j = 0; j < m; j++) {               // m uniform per 8-lane group
            int   sj = __shfl(cx, (g << 3) | j, 64);
            float wj = __shfl(cy, (g << 3) | j, 64);
            uint4 q = *(const uint4*)(x + (size_t)sj * DIM + sub * 8);
            const __half2* hp = (const __half2*)&q;
            #pragma unroll
            for (int k = 0; k < 4; k++) {
                float2 f = __half22float2(hp[k]);
                acc[2 * k]     += f.x * wj;
                acc[2 * k + 1] += f.y * wj;
            }
        }
    }
}

__global__ void k_conv1(const __half* __restrict__ x0h,
                        const u32* __restrict__ row_ptr,
                        const u32* __restrict__ colw,
                        __half* __restrict__ x1h, int N) {
    int wave = (blockIdx.x * 256 + threadIdx.x) >> 6;
    int g    = (threadIdx.x >> 3) & 7;
    int sub  = threadIdx.x & 7;
    int row  = wave * 8 + g;
    if (row >= N) return;
    u32 s = row_ptr[row], e = row_ptr[row + 1];
    float acc[8] = {0, 0, 0, 0, 0, 0, 0, 0};
    gather8(x0h, colw, s, e, g, sub, acc);
    float rdeno = 1.0f / fmaxf((float)(e - s), 1.0f);
    __half2 hv[4];
    #pragma unroll
    for (int k = 0; k < 4; k++) {
        float v0 = acc[2 * k] * rdeno;
        float v1 = acc[2 * k + 1] * rdeno;
        v0 = (v0 >= 0.0f) ? v0 : NEG_SLOPE * v0;
        v1 = (v1 >= 0.0f) ? v1 : NEG_SLOPE * v1;
        hv[k] = __floats2half2_rn(v0, v1);
    }
    *(uint4*)(x1h + (size_t)row * DIM + sub * 8) = *(const uint4*)hv;
}

__global__ void k_conv2(const __half* __restrict__ x0h,
                        const __half* __restrict__ x1h,
                        const u32* __restrict__ row_ptr,
                        const u32* __restrict__ colw,
                        float* __restrict__ out, int N) {
    int wave = (blockIdx.x * 256 + threadIdx.x) >> 6;
    int g    = (threadIdx.x >> 3) & 7;
    int sub  = threadIdx.x & 7;
    int row  = wave * 8 + g;
    if (row >= N) return;
    u32 s = row_ptr[row], e = row_ptr[row + 1];
    // hoist own-row loads so they overlap the gather latency
    uint4 q0 = *(const uint4*)(x0h + (size_t)row * DIM + sub * 8);
    uint4 q1 = *(const uint4*)(x1h + (size_t)row * DIM + sub * 8);
    float acc[8] = {0, 0, 0, 0, 0, 0, 0, 0};
    gather8(x1h, colw, s, e, g, sub, acc);
    float rdeno = 1.0f / fmaxf((float)(e - s), 1.0f);
    const __half2* h0 = (const __half2*)&q0;
    const __half2* h1 = (const __half2*)&q1;
    float r[8];
    #pragma unroll
    for (int k = 0; k < 4; k++) {
        float2 a = __half22float2(h0[k]);
        float2 b = __half22float2(h1[k]);
        float x2a = acc[2 * k] * rdeno;
        float x2b = acc[2 * k + 1] * rdeno;
        x2a = (x2a >= 0.0f) ? x2a : NEG_SLOPE * x2a;
        x2b = (x2b >= 0.0f) ? x2b : NEG_SLOPE * x2b;
        r[2 * k]     = a.x + b.x + x2a;
        r[2 * k + 1] = a.y + b.y + x2b;
    }
    float* op = out + (size_t)row * DIM + sub * 8;
    *(float4*)(op)     = make_float4(r[0], r[1], r[2], r[3]);
    *(float4*)(op + 4) = make_float4(r[4], r[5], r[6], r[7]);
}

static inline size_t align16(size_t x) { return (x + 15) & ~(size_t)15; }

extern "C" void kernel_launch(void* const* d_in, const int* in_sizes, int n_in,
                              void* d_out, int out_size, void* d_ws, size_t ws_size,
                              hipStream_t stream) {
    const int N = in_sizes[0] / DIM;      // 200000
    const int E = in_sizes[1] / 2;        // 600000

    const float* emb = (const float*)d_in[0];
    const int*   ei  = (const int*)d_in[1];
    const float* w   = (const float*)d_in[2];
    float*       out = (float*)d_out;

    const int B     = (N + BKT - 1) / BKT;          // 782 buckets
    const int nblkE = (E + TILEP - 1) / TILEP;      // 147 pair tiles
    const int M     = B * nblkE;                    // 114,954
    const int nb1   = (M + STILE - 1) / STILE;      // 57 (<=256)
    const int rb    = (N + 31) / 32;                // 6250 norm blocks (512 thr)
    const int cvb   = (N + 31) / 32;                // conv blocks: 32 rows/block

    char* ws = (char*)d_ws;
    size_t off = 0;
    __half* x0h    = (__half*)(ws + off); off += align16((size_t)N * DIM * 2);
    __half* x1h    = (__half*)(ws + off); off += align16((size_t)N * DIM * 2);
    u32*    pay    = (u32*)(ws + off);    off += align16((size_t)2 * E * 4);
    u8*     loc8   = (u8*)(ws + off);     off += align16((size_t)2 * E);
    u32*    colw   = (u32*)(ws + off);    off += align16((size_t)2 * E * 4);
    u32*    mat    = (u32*)(ws + off);    off += align16((size_t)M * 4);
    u32*    mscan  = (u32*)(ws + off);    off += align16((size_t)M * 4);
    u32*    row_ptr= (u32*)(ws + off);    off += align16((size_t)(N + 1) * 4);
    u32*    bsum   = (u32*)(ws + off);    off += align16(256 * 4);

    k_norm_hist<<<rb + nblkE, 512, 0, stream>>>(emb, x0h, ei, mat, N, E, rb, B, nblkE);
    k_scan1  <<<nb1, 256, 0, stream>>>(mat, mscan, bsum, M);
    k_scanfix<<<(M + 255) / 256, 256, 0, stream>>>(mscan, bsum, nb1, M);
    k_place  <<<nblkE, 512, 0, stream>>>(ei, w, mscan, pay, loc8, E, nblkE, B);
    k_bucket <<<B, 256, 0, stream>>>(pay, loc8, mscan, row_ptr, colw, N, E, B, nblkE);

    k_conv1<<<cvb, 256, 0, stream>>>(x0h, row_ptr, colw, x1h, N);
    k_conv2<<<cvb, 256, 0, stream>>>(x0h, x1h, row_ptr, colw, out, N);
}

// Round 11
// 205.369 us; speedup vs baseline: 1.0286x; 1.0286x over previous
//
#include <hip/hip_runtime.h>
#include <hip/hip_fp16.h>

#define DIM 64
#define NEG_SLOPE 0.01f
#define BKT 256          // nodes per bucket (LDS hist granularity in k_bucket)
#define TILEP 4096       // symmetric PAIRS per hist/place tile (= 8192 records)
#define RECS (TILEP * 2) // records per tile

typedef unsigned u32;
typedef unsigned short u16;
typedef unsigned char u8;

// ---------------------------------------------------------------------------
// Round 19: kill the scan machinery. R18 ledger: convs pinned at the
// random-line floor (41.7us, 4 variants identical); ~60-70us of the total is
// launch overhead + small fixed-cost kernels across 7 launches. The
// mat/mscan scan (2 launches, 460KB x3 traffic) only bought deterministic
// tile ordering — worthless, since within-bin rank order was already
// nondeterministic. New build:
//   memset(ghist+gcur)            -- 6.4KB, graph-capturable
//   k_norm_hist: norm | LDS hist -> atomicAdd into global ghist[782]
//   k_place: inline 782-scan of ghist (blk0 publishes gbase[]); per-bin
//            atomic reservation gbase[bin]+atomicAdd(&gcur[bin],cnt);
//            LDS sort + coalesced run write-out as before
//   k_bucket: seg bounds = gbase[b..b+1]; R13-exact (staging reverted: -7us)
// 5 kernels + 1 memset (was 7 kernels). Convs = R13-exact.
// ---------------------------------------------------------------------------

__global__ void k_norm_hist(const float* __restrict__ emb,
                            __half* __restrict__ x0h,
                            const int* __restrict__ p,
                            u32* __restrict__ ghist,
                            int N, int E, int rb, int B) {
    int t = threadIdx.x;
    if ((int)blockIdx.x < rb) {
        // L2-normalize: 16 lanes/row, 4 rows/wave, 8 waves -> 32 rows/block
        int lane = t & 63;
        int row  = blockIdx.x * 32 + (t >> 6) * 4 + (lane >> 4);
        int l16  = lane & 15;
        if (row >= N) return;
        float4 v = *(const float4*)(emb + (size_t)row * DIM + l16 * 4);
        float s = v.x * v.x + v.y * v.y + v.z * v.z + v.w * v.w;
        #pragma unroll
        for (int m = 1; m < 16; m <<= 1) s += __shfl_xor(s, m, 64);
        float inv = 1.0f / fmaxf(sqrtf(s), 1e-12f);
        union { uint2 u; __half2 h[2]; } pk;
        pk.h[0] = __floats2half2_rn(v.x * inv, v.y * inv);
        pk.h[1] = __floats2half2_rn(v.z * inv, v.w * inv);
        *(uint2*)(x0h + (size_t)row * DIM + l16 * 4) = pk.u;
    } else {
        __shared__ u32 hist[800];           // B = 782 bins
        int blk = blockIdx.x - rb;
        for (int i = t; i < B; i += 512) hist[i] = 0;
        __syncthreads();
        int base = blk * TILEP;
        #pragma unroll
        for (int k = 0; k < TILEP / 512; k++) {
            int pe = base + k * 512 + t;
            if (pe < E) {
                int a = p[pe];
                int b = p[pe + E];
                atomicAdd(&hist[(u32)b >> 8], 1u);
                atomicAdd(&hist[(u32)a >> 8], 1u);
            }
        }
        __syncthreads();
        // flush to global histogram (147 adds per address, low contention)
        for (int i = t; i < B; i += 512)
            if (hist[i]) atomicAdd(&ghist[i], hist[i]);
    }
}

// LDS tile sort + atomic per-bin reservation + coalesced run write-out.
// ~94KB LDS, 1 block/CU.
__global__ __launch_bounds__(512, 1)
void k_place(const int* __restrict__ p, const float* __restrict__ w,
             const u32* __restrict__ ghist, u32* __restrict__ gcur,
             u32* __restrict__ gbase,
             u32* __restrict__ pay, u8* __restrict__ loc8,
             int E, int B) {
    __shared__ u32 sPay[RECS];    // 32KB
    __shared__ u32 sMeta[RECS];   // 32KB (= dst node id; bin=>>8, loc=&255)
    __shared__ u16 sPerm[RECS];   // 16KB
    __shared__ u32 hist[1024];    // counts -> (rezeroed) rank cursors
    __shared__ u32 sstart[1024];  // local exclusive bin starts
    __shared__ u32 delta[1024];   // global base (phase 0) -> slot delta
    __shared__ u32 sdata[512];

    int blk = blockIdx.x;
    int t = threadIdx.x;
    int base = blk * TILEP;
    int rem = E - base;                       // pairs in this tile
    int vlim = rem * 2; if (vlim > RECS) vlim = RECS;

    // phase 0: inline exclusive scan of ghist[0..B) -> delta[] = global bases
    u32 g0 = (2 * t     < B) ? ghist[2 * t]     : 0u;
    u32 g1 = (2 * t + 1 < B) ? ghist[2 * t + 1] : 0u;
    u32 gts = g0 + g1;
    sdata[t] = gts;
    __syncthreads();
    for (int off = 1; off < 512; off <<= 1) {
        u32 x = (t >= off) ? sdata[t - off] : 0u;
        __syncthreads();
        sdata[t] += x;
        __syncthreads();
    }
    u32 gexcl = sdata[t] - gts;
    delta[2 * t]     = gexcl;
    delta[2 * t + 1] = gexcl + g0;
    __syncthreads();
    if (blk == 0) {                 // publish bases for k_bucket
        for (int i = t; i < B; i += 512) gbase[i] = delta[i];
        if (t == 0) gbase[B] = (u32)(2 * E);
    }

    hist[t] = 0; hist[t + 512] = 0;
    __syncthreads();

    // pass A: stage records + count bins
    #pragma unroll
    for (int k = 0; k < TILEP / 512; k++) {
        int pe = base + k * 512 + t;
        if (pe < E) {
            int a = p[pe];
            int b = p[pe + E];
            float wf = w[pe];
            float wb = w[pe + E];
            u32 wf14 = (u32)(wf * 16384.0f + 0.5f); if (wf14 > 16383u) wf14 = 16383u;
            u32 wb14 = (u32)(wb * 16384.0f + 0.5f); if (wb14 > 16383u) wb14 = 16383u;
            int li = (k * 512 + t) * 2;
            sPay[li]      = ((u32)a << 14) | wf14;   // fwd record: dst = b
            sMeta[li]     = (u32)b;
            sPay[li + 1]  = ((u32)b << 14) | wb14;   // bwd record: dst = a
            sMeta[li + 1] = (u32)a;
            atomicAdd(&hist[(u32)b >> 8], 1u);
            atomicAdd(&hist[(u32)a >> 8], 1u);
        }
    }
    __syncthreads();

    // local scan of 1024 bins (2/thread) -> sstart (hist preserved)
    u32 a0 = hist[2 * t], a1 = hist[2 * t + 1];
    u32 tsum = a0 + a1;
    sdata[t] = tsum;
    __syncthreads();
    for (int off = 1; off < 512; off <<= 1) {
        u32 x = (t >= off) ? sdata[t - off] : 0u;
        __syncthreads();
        sdata[t] += x;
        __syncthreads();
    }
    u32 texcl = sdata[t] - tsum;
    sstart[2 * t]     = texcl;
    sstart[2 * t + 1] = texcl + a0;
    __syncthreads();

    // atomic per-bin reservation: delta[i] := gbase[i] + offset - sstart[i]
    for (int i = t; i < B; i += 512) {
        u32 cnt = hist[i];
        if (cnt) {
            u32 off0 = atomicAdd(&gcur[i], cnt);
            delta[i] = delta[i] + off0 - sstart[i];
        }
    }
    __syncthreads();
    hist[t] = 0; hist[t + 512] = 0;   // becomes rank cursor
    __syncthreads();

    // pass B: build permutation (staging order sorted by bin)
    #pragma unroll
    for (int k = 0; k < RECS / 512; k++) {
        int li = k * 512 + t;
        if (li < vlim) {
            u32 bin = sMeta[li] >> 8;
            u32 r = atomicAdd(&hist[bin], 1u);
            sPerm[sstart[bin] + r] = (u16)li;
        }
    }
    __syncthreads();

    // pass C: write out in sorted order; consecutive j -> consecutive gslot
    #pragma unroll
    for (int k = 0; k < RECS / 512; k++) {
        int j = k * 512 + t;
        if (j < vlim) {
            int li = sPerm[j];
            u32 pv = sPay[li];
            u32 mt = sMeta[li];
            u32 gs = (u32)j + delta[mt >> 8];   // u32 wrap arithmetic ok
            pay[gs]  = pv;
            loc8[gs] = (u8)(mt & 255u);
        }
    }
}

__global__ void k_bucket(const u32* __restrict__ pay,
                         const u8* __restrict__ loc8,
                         const u32* __restrict__ gbase,
                         u32* __restrict__ row_ptr,
                         u32* __restrict__ colw,
                         int N, int E, int B) {
    __shared__ u32 hist[BKT];
    __shared__ u32 excl[BKT];
    __shared__ u32 sdata[256];
    int b = blockIdx.x;
    int t = threadIdx.x;
    int node0 = b * BKT;
    int nnodes = N - node0; if (nnodes > BKT) nnodes = BKT;
    u32 seg_s = gbase[b];
    u32 seg_e = gbase[b + 1];
    hist[t] = 0;
    __syncthreads();
    for (u32 j = seg_s + t; j < seg_e; j += 256)
        atomicAdd(&hist[loc8[j]], 1u);
    __syncthreads();
    u32 tsum = hist[t];
    sdata[t] = tsum;
    __syncthreads();
    for (int off = 1; off < 256; off <<= 1) {
        u32 x = (t >= off) ? sdata[t - off] : 0u;
        __syncthreads();
        sdata[t] += x;
        __syncthreads();
    }
    u32 texcl = sdata[t] - tsum;
    excl[t] = texcl;
    if (t < nnodes) row_ptr[node0 + t] = seg_s + texcl;
    if (b == 0 && t == 0) row_ptr[N] = (u32)(2 * E);
    __syncthreads();
    for (u32 j = seg_s + t; j < seg_e; j += 256) {
        u32 loc = loc8[j];
        u32 pos = atomicAdd(&excl[loc], 1u);
        colw[seg_s + pos] = pay[j];
    }
}

// --- conv: 8 rows/wave, 8 lanes/row, lane covers dims [sub*8, sub*8+8) ----
// Simple m-loop gather (proven equal-best: VGPR 24, ~58% occ, conv2 41.7us;
// conv is HBM-random-line-bound, more MLP does not help — R15/R16).

__device__ __forceinline__ void gather8(const __half* __restrict__ x,
                                        const u32* __restrict__ colw,
                                        u32 s, u32 e, int g, int sub,
                                        float acc[8]) {
    for (u32 base = s; base < e; base += 8) {
        int m = (int)(e - base); if (m > 8) m = 8;   // valid edges this chunk
        u32 u = 0;
        if (sub < m) u = colw[base + sub];
        int   cx = (int)(u >> 14);
        float cy = (float)(u & 16383u) * (1.0f / 16384.0f);
        for (int j = 0; j < m; j++) {               // m uniform per 8-lane group
            int   sj = __shfl(cx, (g << 3) | j, 64);
            float wj = __shfl(cy, (g << 3) | j, 64);
            uint4 q = *(const uint4*)(x + (size_t)sj * DIM + sub * 8);
            const __half2* hp = (const __half2*)&q;
            #pragma unroll
            for (int k = 0; k < 4; k++) {
                float2 f = __half22float2(hp[k]);
                acc[2 * k]     += f.x * wj;
                acc[2 * k + 1] += f.y * wj;
            }
        }
    }
}

__global__ void k_conv1(const __half* __restrict__ x0h,
                        const u32* __restrict__ row_ptr,
                        const u32* __restrict__ colw,
                        __half* __restrict__ x1h, int N) {
    int wave = (blockIdx.x * 256 + threadIdx.x) >> 6;
    int g    = (threadIdx.x >> 3) & 7;
    int sub  = threadIdx.x & 7;
    int row  = wave * 8 + g;
    if (row >= N) return;
    u32 s = row_ptr[row], e = row_ptr[row + 1];
    float acc[8] = {0, 0, 0, 0, 0, 0, 0, 0};
    gather8(x0h, colw, s, e, g, sub, acc);
    float rdeno = 1.0f / fmaxf((float)(e - s), 1.0f);
    __half2 hv[4];
    #pragma unroll
    for (int k = 0; k < 4; k++) {
        float v0 = acc[2 * k] * rdeno;
        float v1 = acc[2 * k + 1] * rdeno;
        v0 = (v0 >= 0.0f) ? v0 : NEG_SLOPE * v0;
        v1 = (v1 >= 0.0f) ? v1 : NEG_SLOPE * v1;
        hv[k] = __floats2half2_rn(v0, v1);
    }
    *(uint4*)(x1h + (size_t)row * DIM + sub * 8) = *(const uint4*)hv;
}

__global__ void k_conv2(const __half* __restrict__ x0h,
                        const __half* __restrict__ x1h,
                        const u32* __restrict__ row_ptr,
                        const u32* __restrict__ colw,
                        float* __restrict__ out, int N) {
    int wave = (blockIdx.x * 256 + threadIdx.x) >> 6;
    int g    = (threadIdx.x >> 3) & 7;
    int sub  = threadIdx.x & 7;
    int row  = wave * 8 + g;
    if (row >= N) return;
    u32 s = row_ptr[row], e = row_ptr[row + 1];
    // hoist own-row loads so they overlap the gather latency
    uint4 q0 = *(const uint4*)(x0h + (size_t)row * DIM + sub * 8);
    uint4 q1 = *(const uint4*)(x1h + (size_t)row * DIM + sub * 8);
    float acc[8] = {0, 0, 0, 0, 0, 0, 0, 0};
    gather8(x1h, colw, s, e, g, sub, acc);
    float rdeno = 1.0f / fmaxf((float)(e - s), 1.0f);
    const __half2* h0 = (const __half2*)&q0;
    const __half2* h1 = (const __half2*)&q1;
    float r[8];
    #pragma unroll
    for (int k = 0; k < 4; k++) {
        float2 a = __half22float2(h0[k]);
        float2 b = __half22float2(h1[k]);
        float x2a = acc[2 * k] * rdeno;
        float x2b = acc[2 * k + 1] * rdeno;
        x2a = (x2a >= 0.0f) ? x2a : NEG_SLOPE * x2a;
        x2b = (x2b >= 0.0f) ? x2b : NEG_SLOPE * x2b;
        r[2 * k]     = a.x + b.x + x2a;
        r[2 * k + 1] = a.y + b.y + x2b;
    }
    float* op = out + (size_t)row * DIM + sub * 8;
    *(float4*)(op)     = make_float4(r[0], r[1], r[2], r[3]);
    *(float4*)(op + 4) = make_float4(r[4], r[5], r[6], r[7]);
}

static inline size_t align16(size_t x) { return (x + 15) & ~(size_t)15; }

extern "C" void kernel_launch(void* const* d_in, const int* in_sizes, int n_in,
                              void* d_out, int out_size, void* d_ws, size_t ws_size,
                              hipStream_t stream) {
    const int N = in_sizes[0] / DIM;      // 200000
    const int E = in_sizes[1] / 2;        // 600000

    const float* emb = (const float*)d_in[0];
    const int*   ei  = (const int*)d_in[1];
    const float* w   = (const float*)d_in[2];
    float*       out = (float*)d_out;

    const int B     = (N + BKT - 1) / BKT;          // 782 buckets
    const int nblkE = (E + TILEP - 1) / TILEP;      // 147 pair tiles
    const int rb    = (N + 31) / 32;                // 6250 norm blocks (512 thr)
    const int cvb   = (N + 31) / 32;                // conv blocks: 32 rows/block

    char* ws = (char*)d_ws;
    size_t off = 0;
    __half* x0h    = (__half*)(ws + off); off += align16((size_t)N * DIM * 2);
    __half* x1h    = (__half*)(ws + off); off += align16((size_t)N * DIM * 2);
    u32*    pay    = (u32*)(ws + off);    off += align16((size_t)2 * E * 4);
    u8*     loc8   = (u8*)(ws + off);     off += align16((size_t)2 * E);
    u32*    colw   = (u32*)(ws + off);    off += align16((size_t)2 * E * 4);
    u32*    gmeta  = (u32*)(ws + off);    off += align16(1600 * 4);  // ghist|gcur
    u32*    gbase  = (u32*)(ws + off);    off += align16(800 * 4);
    u32*    row_ptr= (u32*)(ws + off);    off += align16((size_t)(N + 1) * 4);

    u32* ghist = gmeta;
    u32* gcur  = gmeta + 800;

    hipMemsetAsync(gmeta, 0, 1600 * 4, stream);
    k_norm_hist<<<rb + nblkE, 512, 0, stream>>>(emb, x0h, ei, ghist, N, E, rb, B);
    k_place <<<nblkE, 512, 0, stream>>>(ei, w, ghist, gcur, gbase, pay, loc8, E, B);
    k_bucket<<<B, 256, 0, stream>>>(pay, loc8, gbase, row_ptr, colw, N, E, B);

    k_conv1<<<cvb, 256, 0, stream>>>(x0h, row_ptr, colw, x1h, N);
    k_conv2<<<cvb, 256, 0, stream>>>(x0h, x1h, row_ptr, colw, out, N);
}